// Round 8
// baseline (339.431 us; speedup 1.0000x reference)
//
#include <hip/hip_runtime.h>
#include <stdint.h>
#include <stddef.h>

// ---------- types ----------
typedef __attribute__((ext_vector_type(4)))  int   i32x4;    // MFMA i8 operand / acc
typedef __attribute__((ext_vector_type(8)))  short bf16x8;
typedef __attribute__((ext_vector_type(4)))  float f32x4;
typedef __attribute__((ext_vector_type(4)))  float f32x4v;
typedef __attribute__((ext_vector_type(4)))  unsigned short u16x4;

__device__ __forceinline__ unsigned short f2bf(float f) {
    union { float f; unsigned u; } v; v.f = f;
    unsigned r = v.u + 0x7FFFu + ((v.u >> 16) & 1u);
    return (unsigned short)(r >> 16);
}

__device__ __forceinline__ void gload_lds16(const void* g, void* l) {
    __builtin_amdgcn_global_load_lds(
        (const __attribute__((address_space(1))) void*)(g),
        (__attribute__((address_space(3))) void*)(l), 16, 0, 0);
}

__device__ __forceinline__ int pack4(float a, float b, float c, float d, float inv) {
    int r0 = ((int)rintf(a * inv)) & 255;
    int r1 = ((int)rintf(b * inv)) & 255;
    int r2 = ((int)rintf(c * inv)) & 255;
    int r3 = ((int)rintf(d * inv)) & 255;
    return r0 | (r1 << 8) | (r2 << 16) | (r3 << 24);
}

// ---------- convert: x fp32 -> int8 per-row dynamic quant (+ sx per row) ----------
__global__ void cvt_x_q8(const float* __restrict__ x, signed char* __restrict__ xq,
                         float* __restrict__ sx, int K) {
    const int row = blockIdx.x;
    const int t   = threadIdx.x;          // 256 threads
    const float* xr = x + (size_t)row * K;
    const int ng = K / 1024;              // f32x4 groups per thread (K=4096 -> 4)

    f32x4v v[8];
    float am = 0.f;
#pragma unroll
    for (int i = 0; i < 8; ++i) {
        if (i < ng) {
            v[i] = __builtin_nontemporal_load(&((const f32x4v*)xr)[i * 256 + t]);
            am = fmaxf(am, fmaxf(fmaxf(fabsf(v[i][0]), fabsf(v[i][1])),
                                 fmaxf(fabsf(v[i][2]), fabsf(v[i][3]))));
        }
    }
#pragma unroll
    for (int m = 32; m >= 1; m >>= 1) am = fmaxf(am, __shfl_xor(am, m, 64));
    __shared__ float red[4];
    const int w = t >> 6;
    if ((t & 63) == 0) red[w] = am;
    __syncthreads();
    am = fmaxf(fmaxf(red[0], red[1]), fmaxf(red[2], red[3]));

    const float inv = (am > 0.f) ? 127.0f / am : 0.f;
    if (t == 0) sx[row] = (am > 0.f) ? am / 127.0f : 0.f;

    int* oq = (int*)(xq + (size_t)row * K);
#pragma unroll
    for (int i = 0; i < 8; ++i)
        if (i < ng) oq[i * 256 + t] = pack4(v[i][0], v[i][1], v[i][2], v[i][3], inv);
}

// ---------- convert: W int32 -> int8 (values already int8-ranged; exact) ----------
__global__ void cvt_w_q8(const int* __restrict__ w, signed char* __restrict__ o, int n4) {
    int i = blockIdx.x * blockDim.x + threadIdx.x;
    int stride = gridDim.x * blockDim.x;
    for (; i < n4; i += stride) {
        i32x4 a = __builtin_nontemporal_load(&((const i32x4*)w)[i]);
        ((int*)o)[i] = (a[0] & 255) | ((a[1] & 255) << 8) | ((a[2] & 255) << 16) | ((a[3] & 255) << 24);
    }
}

// =====================================================================
// 128x128 int8 GEMM v8: 64 KiB LDS -> 2 blocks/CU (TLP covers barrier
// drains + ds_read latency that kept v7's 1-block/CU at 49% MfmaUtil).
// All proven components preserved byte-compatible:
//  - 128B LDS rows, both-sides XOR swizzle (chunk16 ^= row&7)  [0 confl]
//  - 16x16x64 i8 MFMA, v5 frag geometry                         [v5/v7]
//  - counted vmcnt (VM2 here: 2 gloads/STG), never drain in loop [T4]
//  - B(t+1) staged at P1-start (full-tile lead); A(t+2) after midBAR
//  - XCD supertile remap (col-major chunk walk)                 [v6]
// 512 thr = 8 waves (2M x 4N), wave tile 64x32, acc 32 VGPR.
// Hazards: B(t+1)->bb^1.B: last read = tile t-1 P1 < its midBAR. SAFE
//          A(t+2)->bb.A after midBAR: bb.A reads all in P1.      SAFE
// Ledger: tile t issues B(t+1)[2]+A(t+2)[2]; at boundary outstanding
//   {A(t+1)2, B(t+1)2, A(t+2)2} -> VM2 drains A(t+1),B(t+1).     OK
// =====================================================================
#define BMT 128
#define BNT 128
#define BKQ 128   // int8 elems per K-tile (=128 B rows)

__global__ __launch_bounds__(512, 4) void gemm128_i8(
    const signed char* __restrict__ A,   // [M][K] i8
    const signed char* __restrict__ Bw,  // [N][K] i8
    const float* __restrict__ sx,        // [M] per-row x scale
    const float* __restrict__ scale_p,
    const float* __restrict__ bias,
    float* __restrict__ C,
    int M, int N, int K)
{
    __shared__ __align__(16) char smem[65536];   // 2 buf x {A 16KB, B 16KB}

    const int t    = threadIdx.x;
    const int lane = t & 63;
    const int w    = t >> 6;
    const int wm   = w >> 2;     // 0..1 (64-row band)
    const int wn   = w & 3;      // 0..3 (32-col band)

    const int ntn = N / BNT;
    const int ntm = M / BMT;
    int nwg = gridDim.x, bid = blockIdx.x;
    int tm, tn;
    if (((nwg & 7) == 0) && (ntm % 8 == 0)) {
        // XCD supertile: XCD x owns tm in [x*tmB,(x+1)*tmB); chunk walks
        // (c%tmB, c/tmB) so same-tn blocks are launch-adjacent -> B L2 reuse.
        const int x = bid & 7, c = bid >> 3;
        const int tmB = ntm >> 3;
        tm = x * tmB + (c % tmB);
        tn = c / tmB;
    } else if ((nwg & 7) == 0) {
        int swz = (bid & 7) * (nwg >> 3) + (bid >> 3);
        tm = swz / ntn; tn = swz % ntn;
    } else {
        tm = bid / ntn; tn = bid % ntn;
    }
    const int row0 = tm * BMT;
    const int col0 = tn * BNT;

    const int Kb = K;                // row stride BYTES (i8)
    const int NT = K / BKQ;

    // staging geometry: one gload covers 64 rows x 128B (512 thr x 16B);
    // source col pre-swizzled, LDS dest linear (both-sides rule #21)
    const int srow = w * 8 + (lane >> 3);               // 0..63
    const int sc2  = ((lane & 7) ^ (lane >> 3)) * 16;   // swizzled col bytes
    const int ldsLaneOff = w * 1024 + lane * 16;

    const char* aG = (const char*)A + (size_t)(row0 + srow) * Kb + sc2;
    const char* bG = (const char*)Bw + (size_t)(col0 + srow) * Kb + sc2;

    // 16x16 frag-read geometry (measured conflict-free)
    const int q    = lane >> 4;        // 0..3 k-chunk
    const int lr   = lane & 15;        // row within 16
    const int swzr = (lr & 7) << 4;    // read-side XOR

    i32x4 acc[4][2] = {};
    i32x4 aF[4][2], bB[2][2];

// stage 128 rows (2 gloads) of A (regoff 0) or B (regoff 16384)
#define STG128(gbase, tj, buf, regoff) do {                                   \
    const char* _g = (gbase) + (size_t)(tj) * 128;                            \
    char* _l = &smem[(buf) * 32768 + (regoff) + ldsLaneOff];                  \
    gload_lds16(_g, _l);                                                      \
    gload_lds16(_g + (size_t)64 * Kb, _l + 8192);                             \
} while (0)

#define RDA(buf, mi, ks) \
    (*(const i32x4*)&smem[(buf) * 32768 + ((wm * 64 + (mi) * 16 + lr) * 128) \
                          + ((((ks) << 6) | (q << 4)) ^ swzr)])
#define RDB(buf, nj, ks) \
    (*(const i32x4*)&smem[(buf) * 32768 + 16384                               \
                          + ((wn * 32 + (nj) * 16 + lr) * 128)                \
                          + ((((ks) << 6) | (q << 4)) ^ swzr)])

#define MFMA_(a, b, c) (c) = __builtin_amdgcn_mfma_i32_16x16x64_i8((a), (b), (c), 0, 0, 0)
#define BAR() __builtin_amdgcn_s_barrier()
#define FENCE() asm volatile("" ::: "memory")
#define VM2() asm volatile("s_waitcnt vmcnt(2)" ::: "memory")
#define VM0() asm volatile("s_waitcnt vmcnt(0)" ::: "memory")
#define VMNONE() do { } while (0)

// One K-tile: {STG B(t+1); reads; MFMA nj0} midBAR {STG A(t+2); MFMA nj1}
// VMW; boundary BAR.  ks-outer MFMA order spaces same-acc dependents by 4.
#define TILE_STEP(tt, bb, stB, stA2, VMW) do {                                        \
    if (stB) STG128(bG, (tt) + 1, (bb) ^ 1, 16384);                                   \
    _Pragma("unroll") for (int mi = 0; mi < 4; ++mi) {                                \
        aF[mi][0] = RDA(bb, mi, 0); aF[mi][1] = RDA(bb, mi, 1); }                     \
    _Pragma("unroll") for (int nj = 0; nj < 2; ++nj) {                                \
        bB[nj][0] = RDB(bb, nj, 0); bB[nj][1] = RDB(bb, nj, 1); }                     \
    __builtin_amdgcn_s_setprio(1);                                                    \
    _Pragma("unroll") for (int ks = 0; ks < 2; ++ks)                                  \
    _Pragma("unroll") for (int mi = 0; mi < 4; ++mi)                                  \
        MFMA_(aF[mi][ks], bB[0][ks], acc[mi][0]);                                     \
    __builtin_amdgcn_s_setprio(0);                                                    \
    BAR(); FENCE();   /* mid: all reads of bb.A complete chip-wide */                 \
    if (stA2) STG128(aG, (tt) + 2, (bb), 0);                                          \
    __builtin_amdgcn_s_setprio(1);                                                    \
    _Pragma("unroll") for (int ks = 0; ks < 2; ++ks)                                  \
    _Pragma("unroll") for (int mi = 0; mi < 4; ++mi)                                  \
        MFMA_(aF[mi][ks], bB[1][ks], acc[mi][1]);                                     \
    __builtin_amdgcn_s_setprio(0);                                                    \
    VMW();                                                                            \
    BAR(); FENCE();   /* boundary: tile t+1 staging landed for all waves */           \
} while (0)

    // prologue: A(0), B(0), A(1); VM2 -> A0,B0 landed, A1 in flight
    STG128(aG, 0, 0, 0);
    STG128(bG, 0, 0, 16384);
    STG128(aG, 1, 1, 0);
    VM2();
    BAR(); FENCE();

    for (int tt = 0; tt < NT - 2; tt += 2) {
        TILE_STEP(tt,     0, 1, 1, VM2);
        TILE_STEP(tt + 1, 1, 1, 1, VM2);
    }
    TILE_STEP(NT - 2, 0, 1, 0, VM0);     // stage B(NT-1) only; full drain
    TILE_STEP(NT - 1, 1, 0, 0, VMNONE);  // pure compute

    // ---- epilogue: y = acc * (sx[row]*s) + bias[col]; plain cached stores ----
    const float s = scale_p[0];
    float bv[2];
#pragma unroll
    for (int nj = 0; nj < 2; ++nj) bv[nj] = bias[col0 + wn * 32 + nj * 16 + lr];
#pragma unroll
    for (int mi = 0; mi < 4; ++mi) {
        const int rbase = row0 + wm * 64 + mi * 16 + q * 4;
        float sxr[4];
#pragma unroll
        for (int j = 0; j < 4; ++j) sxr[j] = sx[rbase + j] * s;
#pragma unroll
        for (int nj = 0; nj < 2; ++nj) {
            const int col = col0 + wn * 32 + nj * 16 + lr;
#pragma unroll
            for (int j = 0; j < 4; ++j)
                C[(size_t)(rbase + j) * N + col] = (float)acc[mi][nj][j] * sxr[j] + bv[nj];
        }
    }
#undef STG128
#undef RDA
#undef RDB
#undef TILE_STEP
}

// ---------- fallback: fused fp32->bf16-in-staging GEMM (ws too small / odd shape) ----------
#define BM 128
#define BN 128
#define BK 64

__global__ __launch_bounds__(256, 2) void gemm_fused(
    const float* __restrict__ A,
    const int* __restrict__ Bw,
    const float* __restrict__ scale_p,
    const float* __restrict__ bias,
    float* __restrict__ C,
    int M, int N, int K)
{
    __shared__ unsigned short As[BM * BK];
    __shared__ unsigned short Bs[BN * BK];
    const int t = threadIdx.x, lane = t & 63, w = t >> 6;
    const int wm = w >> 1, wn = w & 1;
    int nwg = gridDim.x, bid = blockIdx.x;
    int swz = (nwg % 8 == 0) ? ((bid & 7) * (nwg >> 3) + (bid >> 3)) : bid;
    const int ntn = N / BN;
    const int row0 = (swz / ntn) * BM, col0 = (swz % ntn) * BN;
    f32x4 acc[4][4] = {};
    const int lr = lane & 15, lkbase = (lane >> 4) * 8;

    for (int kt = 0; kt < K; kt += BK) {
#pragma unroll
        for (int i = 0; i < 8; ++i) {
            const int r = i * 16 + (t >> 4), c = (t & 15) * 4;
            f32x4v v = *(const f32x4v*)&A[(size_t)(row0 + r) * K + kt + c];
            u16x4 o; o[0] = f2bf(v[0]); o[1] = f2bf(v[1]); o[2] = f2bf(v[2]); o[3] = f2bf(v[3]);
            *(u16x4*)&As[r * BK + c] = o;
        }
#pragma unroll
        for (int i = 0; i < 8; ++i) {
            const int r = i * 16 + (t >> 4), c = (t & 15) * 4;
            i32x4 v = *(const i32x4*)&Bw[(size_t)(col0 + r) * K + kt + c];
            u16x4 o; o[0] = f2bf((float)v[0]); o[1] = f2bf((float)v[1]);
                     o[2] = f2bf((float)v[2]); o[3] = f2bf((float)v[3]);
            *(u16x4*)&Bs[r * BK + c] = o;
        }
        __syncthreads();
#pragma unroll
        for (int ks = 0; ks < 2; ++ks) {
            bf16x8 af[4], bfr[4];
#pragma unroll
            for (int m = 0; m < 4; ++m) af[m] = *(const bf16x8*)&As[(wm * 64 + m * 16 + lr) * BK + lkbase + ks * 32];
#pragma unroll
            for (int n = 0; n < 4; ++n) bfr[n] = *(const bf16x8*)&Bs[(wn * 64 + n * 16 + lr) * BK + lkbase + ks * 32];
#pragma unroll
            for (int m = 0; m < 4; ++m)
#pragma unroll
                for (int n = 0; n < 4; ++n)
                    acc[m][n] = __builtin_amdgcn_mfma_f32_16x16x32_bf16(af[m], bfr[n], acc[m][n], 0, 0, 0);
        }
        __syncthreads();
    }
    const float s = scale_p[0];
    const int lq4 = (lane >> 4) * 4;
#pragma unroll
    for (int m = 0; m < 4; ++m)
#pragma unroll
        for (int n = 0; n < 4; ++n) {
            const int col = col0 + wn * 64 + n * 16 + lr;
            const float bv = bias[col];
#pragma unroll
            for (int j = 0; j < 4; ++j) {
                const int row = row0 + wm * 64 + m * 16 + lq4 + j;
                C[(size_t)row * N + col] = acc[m][n][j] * s + bv;
            }
        }
}

extern "C" void kernel_launch(void* const* d_in, const int* in_sizes, int n_in,
                              void* d_out, int out_size, void* d_ws, size_t ws_size,
                              hipStream_t stream) {
    const float* x     = (const float*)d_in[0];
    const int*   w8    = (const int*)d_in[1];
    const float* scale = (const float*)d_in[2];
    const float* bias  = (const float*)d_in[3];
    float* out = (float*)d_out;

    const int N = in_sizes[3];                    // 16384
    const int K = (int)((long)in_sizes[1] / N);   // 4096
    const int M = (int)((long)in_sizes[0] / K);   // 4096

    const size_t needA = (size_t)M * K;           // i8
    const size_t needB = (size_t)N * K;           // i8
    const size_t needS = (size_t)M * sizeof(float);
    const int NT = K / BKQ;

    const bool okShape = (M % BMT == 0) && (N % BNT == 0) && (K % BKQ == 0) &&
                         (K % 1024 == 0) && (K / 1024 <= 8) &&
                         (NT >= 4) && ((NT & 1) == 0);

    if (okShape && ws_size >= needA + needB + needS) {
        signed char* Aq = (signed char*)d_ws;
        signed char* Bq = Aq + needA;
        float*       sx = (float*)(Bq + needB);
        cvt_x_q8<<<M, 256, 0, stream>>>(x, Aq, sx, K);
        cvt_w_q8<<<4096, 256, 0, stream>>>(w8, Bq, (int)((size_t)N * K / 4));
        const int nblocks = (M / BMT) * (N / BNT);
        gemm128_i8<<<nblocks, 512, 0, stream>>>(Aq, Bq, sx, scale, bias, out, M, N, K);
    } else {
        const int nblocks = (M / BM) * (N / BN);
        gemm_fused<<<nblocks, 256, 0, stream>>>(x, w8, scale, bias, out, M, N, K);
    }
}